// Round 9
// baseline (210.928 us; speedup 1.0000x reference)
//
#include <hip/hip_runtime.h>
#include <hip/hip_bf16.h>
#include <math.h>

// B=8, S=8, H=512, W=512
#define HW (512 * 512)
#define CELLS 64
#define BLOCK 256
#define GRID 1024          // 4 blocks/CU, one co-resident generation
#define NSTEP 8
#define STEP_ELTS 2048     // per block per step (2 float4 / thread)
// Sweep layout: step s, block b covers flat chunk_id = s*GRID + b, i.e.
// [(s*GRID+b)*2048, +2048). Whole grid sweeps ONE contiguous 8 MB window per
// array per step (DRAM row locality test, clean: NO atomics this time).
// cell = chunk_id/128 = 8*s + (b>>7); block b touches cells {8s + g}, g=b>>7.
// Presence skip: step s skipped entirely when pres[8s+g]==0.

// t in {0,1}; p = sigmoid(seg_logits) is an input, so bce_with_logits(x,t)
// == -log(pt), pt = t ? p : 1-p (exact identity). Raw log-sums; negate later.
__device__ __forceinline__ void accum4(float4 pv, float4 tv, float4 av,
                                       float& slog, float& sfn, float& si,
                                       float& sp, float& st, float& sa)
{
#pragma unroll
    for (int j = 0; j < 4; ++j) {
        float p = ((const float*)&pv)[j];
        float t = ((const float*)&tv)[j];
        float a = ((const float*)&av)[j];
        bool tpos = (t > 0.5f);

        float pt = tpos ? p : 1.f - p;
        float la = __logf(pt);          // = -bce
        float om = 1.f - pt;

        slog += la;
        sfn  += om * om * la;
        si    = fmaf(p, t, si);
        sp   += p;
        st   += t;

        float aa = tpos ? a : 1.f - a;  // a in [1e-4, 1-1e-4]
        sa += fmaxf(__logf(aa), -100.f);
    }
}

// ws layout: [GRID][48] floats = per-block, per-step {slog,sfn,si,sp,st,sa}.
__global__ __launch_bounds__(BLOCK, 4) void partial_kernel(
    const float* __restrict__ pg,   // seg_probs
    const float* __restrict__ tg,   // seg_targets
    const float* __restrict__ ag,   // attention_maps
    const int* __restrict__ presence_targets,
    float* __restrict__ ws)
{
    __shared__ float red[4][NSTEP][6];   // [wave][step][component]

    const int tid  = threadIdx.x;
    const int wv   = tid >> 6;
    const int lane = tid & 63;
    const int b    = blockIdx.x;
    const int g    = b >> 7;

    for (int i = tid; i < 4 * NSTEP * 6; i += BLOCK) ((float*)red)[i] = 0.f;

    // valid (present) steps for this block
    int vs[NSTEP]; int nv = 0;
#pragma unroll
    for (int s = 0; s < NSTEP; ++s)
        if (presence_targets[8 * s + g] != 0) vs[nv++] = s;

    __syncthreads();   // red zeroed before any wave writes its slots

    auto addr = [&](int s) -> size_t {
        return ((size_t)s * GRID + b) * STEP_ELTS + ((size_t)tid << 2);
    };

    float4 Pa, Ta, Aa, Pb, Tb, Ab;
    if (nv > 0) {
        const size_t o = addr(vs[0]);
        Pa = *(const float4*)(pg + o);  Pb = *(const float4*)(pg + o + 1024);
        Ta = *(const float4*)(tg + o);  Tb = *(const float4*)(tg + o + 1024);
        Aa = *(const float4*)(ag + o);  Ab = *(const float4*)(ag + o + 1024);
    }

    for (int i = 0; i < nv; ++i) {
        float4 cPa = Pa, cTa = Ta, cAa = Aa, cPb = Pb, cTb = Tb, cAb = Ab;
        if (i + 1 < nv) {
            const size_t o = addr(vs[i + 1]);
            Pa = *(const float4*)(pg + o);  Pb = *(const float4*)(pg + o + 1024);
            Ta = *(const float4*)(tg + o);  Tb = *(const float4*)(tg + o + 1024);
            Aa = *(const float4*)(ag + o);  Ab = *(const float4*)(ag + o + 1024);
        }

        float slog = 0.f, sfn = 0.f, si = 0.f, sp = 0.f, st = 0.f, sa = 0.f;
        accum4(cPa, cTa, cAa, slog, sfn, si, sp, st, sa);
        accum4(cPb, cTb, cAb, slog, sfn, si, sp, st, sa);

#pragma unroll
        for (int o = 32; o > 0; o >>= 1) {
            slog += __shfl_down(slog, o);
            sfn  += __shfl_down(sfn, o);
            si   += __shfl_down(si, o);
            sp   += __shfl_down(sp, o);
            st   += __shfl_down(st, o);
            sa   += __shfl_down(sa, o);
        }
        if (lane == 0) {
            const int s = vs[i];
            red[wv][s][0] = slog; red[wv][s][1] = sfn; red[wv][s][2] = si;
            red[wv][s][3] = sp;   red[wv][s][4] = st;  red[wv][s][5] = sa;
        }
    }

    __syncthreads();
    if (tid < NSTEP * 6) {   // tid = s*6 + k
        const int s = tid / 6, k = tid % 6;
        float v = red[0][s][k] + red[1][s][k] + red[2][s][k] + red[3][s][k];
        ws[(size_t)b * 48 + tid] = v;   // all 48 slots written (zeros if skipped)
    }
}

// -------- Kernel 2: combine partials + small arrays -> scalar --------
// cell c: s = c>>3, g = c&7, blocks b = g*128 + j (j=0..127), slot s.
__global__ __launch_bounds__(64) void finalize_kernel(
    const float* __restrict__ ws,
    const float* __restrict__ presence_probs,
    const int* __restrict__ presence_targets,
    float* __restrict__ out)
{
    const int c = threadIdx.x;  // cell id, 0..63 (one wave)
    const int s = c >> 3, g = c & 7;

    float slog = 0.f, sfn = 0.f, si = 0.f, sp = 0.f, st = 0.f, sa = 0.f;
    const float* w = ws + ((size_t)g * 128) * 48 + s * 6;
    for (int j = 0; j < 128; ++j) {
        slog += w[0]; sfn += w[1]; si += w[2];
        sp   += w[3]; st  += w[4]; sa += w[5];
        w += 48;
    }
    float sb = -slog, sf = -sfn, satt = -sa;

    const float invHW = 1.0f / (float)HW;
    float bce_mean   = sb * invHW;
    float focal_mean = 0.25f * sf * invHW;
    float att_mean   = satt * invHW;
    float dice = 1.f - (2.f * si + 1e-6f) / (sp + st + 1e-6f);

    float pres = (float)presence_targets[c];
    float pp   = presence_probs[c];

    float lp = fmaxf(logf(pp), -100.f);
    float lq = fmaxf(log1pf(-pp), -100.f);
    float absence = -(pres * lp + (1.f - pres) * lq);

    bool wrong = (pres == 0.f && pp > 0.5f) || (pres == 1.f && pp < 0.5f);
    float dm = pp - 0.5f;
    float conf = wrong ? dm * dm : 0.f;

    float cnt = pres;
    float mb = bce_mean * pres;
    float md = dice * pres;
    float mf = focal_mean * pres;
    float ma = att_mean * pres;

#pragma unroll
    for (int o = 32; o > 0; o >>= 1) {
        cnt     += __shfl_down(cnt, o);
        mb      += __shfl_down(mb, o);
        md      += __shfl_down(md, o);
        mf      += __shfl_down(mf, o);
        ma      += __shfl_down(ma, o);
        absence += __shfl_down(absence, o);
        conf    += __shfl_down(conf, o);
    }

    if (threadIdx.x == 0) {
        const float inv_n = 1.0f / (float)CELLS;
        float safe = fmaxf(cnt, 1.f);
        float seg  = (cnt > 0.f) ? mb / safe : 0.f;
        float dce  = (cnt > 0.f) ? md / safe : 0.f;
        float foc  = (cnt > 0.f) ? mf / safe : 0.f;
        float total = 1.0f * seg
                    + 1.0f * dce
                    + 0.5f * foc
                    + 1.0f * (absence * inv_n)
                    + 0.5f * (ma * inv_n)
                    + 0.1f * (conf * inv_n);
        out[0] = total;
    }
}

extern "C" void kernel_launch(void* const* d_in, const int* in_sizes, int n_in,
                              void* d_out, int out_size, void* d_ws, size_t ws_size,
                              hipStream_t stream) {
    const float* seg_probs        = (const float*)d_in[1];
    const float* seg_targets      = (const float*)d_in[2];
    const float* presence_probs   = (const float*)d_in[3];
    const float* attention_maps   = (const float*)d_in[4];
    const int*   presence_targets = (const int*)d_in[5];
    float* ws = (float*)d_ws;

    partial_kernel<<<GRID, BLOCK, 0, stream>>>(
        seg_probs, seg_targets, attention_maps, presence_targets, ws);
    finalize_kernel<<<1, 64, 0, stream>>>(
        ws, presence_probs, presence_targets, (float*)d_out);
}

// Round 10
// 207.021 us; speedup vs baseline: 1.0189x; 1.0189x over previous
//
#include <hip/hip_runtime.h>
#include <hip/hip_bf16.h>
#include <math.h>

// Problem constants (from reference): B=8, S=8, H=512, W=512
#define HW (512 * 512)
#define CELLS 64          // B*S
#define KCH 32            // blocks per cell
#define CHUNK (HW / KCH)  // 8192 elements per block
#define BLOCK 256

// t in {0,1}; p = sigmoid(seg_logits) is an input, so bce_with_logits(x,t)
// == -log(pt), pt = t ? p : 1-p (exact identity). Sum log terms; negate at write.
__device__ __forceinline__ void accum4(float4 pv, float4 tv, float4 av,
                                       float& slog, float& sfn, float& si,
                                       float& sp, float& st, float& sa)
{
#pragma unroll
    for (int j = 0; j < 4; ++j) {
        float p = ((const float*)&pv)[j];
        float t = ((const float*)&tv)[j];
        float a = ((const float*)&av)[j];
        bool tpos = (t > 0.5f);

        float pt = tpos ? p : 1.f - p;
        float la = __logf(pt);          // = -bce
        float om = 1.f - pt;

        slog += la;
        sfn  += om * om * la;
        si    = fmaf(p, t, si);
        sp   += p;
        st   += t;

        float aa = tpos ? a : 1.f - a;  // a in [1e-4, 1-1e-4]
        sa += fmaxf(__logf(aa), -100.f);
    }
}

// -------- Kernel 1: per-chunk partial sums over the 3 big arrays --------
// ALGORITHMIC SKIP: all big-array loss terms are multiplied by pres[cell]
// (presence_targets, an input). pres==0 cells contribute exactly zero from
// the spatial arrays -> skip their reads entirely (~50% of traffic).
// ws layout: [CELLS*KCH][8] floats: {sum_bce, sum_focal, si, sp, st, sum_att, -, -}
__global__ __launch_bounds__(BLOCK) void partial_kernel(
    const float* __restrict__ pg,   // seg_probs
    const float* __restrict__ tg,   // seg_targets
    const float* __restrict__ ag,   // attention_maps
    const int* __restrict__ presence_targets,
    float* __restrict__ ws)
{
    const int cell  = blockIdx.x >> 5;       // / KCH
    const int chunk = blockIdx.x & (KCH - 1);

    if (presence_targets[cell] == 0) {
        // exact-zero contribution; write zeros (don't rely on ws poison value)
        if (threadIdx.x == 0) {
            float* o = ws + (size_t)blockIdx.x * 8;
            o[0] = 0.f; o[1] = 0.f; o[2] = 0.f;
            o[3] = 0.f; o[4] = 0.f; o[5] = 0.f;
        }
        return;
    }

    const size_t base = (size_t)cell * HW + (size_t)chunk * CHUNK;

    const float4* p4 = (const float4*)(pg + base);
    const float4* t4 = (const float4*)(tg + base);
    const float4* a4 = (const float4*)(ag + base);

    float slog = 0.f, sfn = 0.f, si = 0.f, sp = 0.f, st = 0.f, sa = 0.f;

    // CHUNK/4 = 2048 float4 per block; 2x unrolled -> 6 loads in flight
    for (int i = threadIdx.x; i < CHUNK / 4; i += 2 * BLOCK) {
        float4 pv0 = p4[i];
        float4 tv0 = t4[i];
        float4 av0 = a4[i];
        float4 pv1 = p4[i + BLOCK];
        float4 tv1 = t4[i + BLOCK];
        float4 av1 = a4[i + BLOCK];
        accum4(pv0, tv0, av0, slog, sfn, si, sp, st, sa);
        accum4(pv1, tv1, av1, slog, sfn, si, sp, st, sa);
    }

    // wave (64-lane) shuffle reduction
#pragma unroll
    for (int o = 32; o > 0; o >>= 1) {
        slog += __shfl_down(slog, o);
        sfn  += __shfl_down(sfn, o);
        si   += __shfl_down(si, o);
        sp   += __shfl_down(sp, o);
        st   += __shfl_down(st, o);
        sa   += __shfl_down(sa, o);
    }

    __shared__ float red[BLOCK / 64][6];
    const int wave = threadIdx.x >> 6;
    const int lane = threadIdx.x & 63;
    if (lane == 0) {
        red[wave][0] = slog; red[wave][1] = sfn; red[wave][2] = si;
        red[wave][3] = sp;   red[wave][4] = st;  red[wave][5] = sa;
    }
    __syncthreads();
    if (threadIdx.x == 0) {
        float r0 = 0, r1 = 0, r2 = 0, r3 = 0, r4 = 0, r5 = 0;
#pragma unroll
        for (int w = 0; w < BLOCK / 64; ++w) {
            r0 += red[w][0]; r1 += red[w][1]; r2 += red[w][2];
            r3 += red[w][3]; r4 += red[w][4]; r5 += red[w][5];
        }
        float* o = ws + (size_t)blockIdx.x * 8;
        o[0] = -r0;  // sum bce
        o[1] = -r1;  // sum om^2*bce
        o[2] = r2;   // sum p*t
        o[3] = r3;   // sum p
        o[4] = r4;   // sum t
        o[5] = -r5;  // sum attention bce
    }
}

// -------- Kernel 2: combine partials + small arrays -> scalar --------
__global__ __launch_bounds__(64) void finalize_kernel(
    const float* __restrict__ ws,
    const float* __restrict__ presence_probs,
    const int* __restrict__ presence_targets,
    float* __restrict__ out)
{
    const int c = threadIdx.x;  // cell id, 0..63 (one wave)

    float sb = 0.f, sf = 0.f, si = 0.f, sp = 0.f, st = 0.f, sa = 0.f;
    const float* w = ws + (size_t)c * KCH * 8;
#pragma unroll 4
    for (int k = 0; k < KCH; ++k) {
        sb += w[0]; sf += w[1]; si += w[2];
        sp += w[3]; st += w[4]; sa += w[5];
        w += 8;
    }

    const float invHW = 1.0f / (float)HW;
    float bce_mean   = sb * invHW;
    float focal_mean = 0.25f * sf * invHW;
    float att_mean   = sa * invHW;
    float dice = 1.f - (2.f * si + 1e-6f) / (sp + st + 1e-6f);

    float pres = (float)presence_targets[c];
    float pp   = presence_probs[c];

    float lp = fmaxf(logf(pp), -100.f);
    float lq = fmaxf(log1pf(-pp), -100.f);
    float absence = -(pres * lp + (1.f - pres) * lq);

    bool wrong = (pres == 0.f && pp > 0.5f) || (pres == 1.f && pp < 0.5f);
    float dm = pp - 0.5f;
    float conf = wrong ? dm * dm : 0.f;

    float cnt = pres;
    float mb = bce_mean * pres;
    float md = dice * pres;      // skipped cells: ws row zeroed -> dice=0, and pres=0 anyway
    float mf = focal_mean * pres;
    float ma = att_mean * pres;

#pragma unroll
    for (int o = 32; o > 0; o >>= 1) {
        cnt     += __shfl_down(cnt, o);
        mb      += __shfl_down(mb, o);
        md      += __shfl_down(md, o);
        mf      += __shfl_down(mf, o);
        ma      += __shfl_down(ma, o);
        absence += __shfl_down(absence, o);
        conf    += __shfl_down(conf, o);
    }

    if (threadIdx.x == 0) {
        const float inv_n = 1.0f / (float)CELLS;
        float safe = fmaxf(cnt, 1.f);
        float seg  = (cnt > 0.f) ? mb / safe : 0.f;
        float dce  = (cnt > 0.f) ? md / safe : 0.f;
        float foc  = (cnt > 0.f) ? mf / safe : 0.f;
        float total = 1.0f * seg
                    + 1.0f * dce
                    + 0.5f * foc
                    + 1.0f * (absence * inv_n)
                    + 0.5f * (ma * inv_n)
                    + 0.1f * (conf * inv_n);
        out[0] = total;
    }
}

extern "C" void kernel_launch(void* const* d_in, const int* in_sizes, int n_in,
                              void* d_out, int out_size, void* d_ws, size_t ws_size,
                              hipStream_t stream) {
    const float* seg_probs        = (const float*)d_in[1];
    const float* seg_targets      = (const float*)d_in[2];
    const float* presence_probs   = (const float*)d_in[3];
    const float* attention_maps   = (const float*)d_in[4];
    const int*   presence_targets = (const int*)d_in[5];
    float* ws = (float*)d_ws;

    partial_kernel<<<CELLS * KCH, BLOCK, 0, stream>>>(
        seg_probs, seg_targets, attention_maps, presence_targets, ws);
    finalize_kernel<<<1, 64, 0, stream>>>(
        ws, presence_probs, presence_targets, (float*)d_out);
}